// Round 1
// baseline (358.559 us; speedup 1.0000x reference)
//
#include <hip/hip_runtime.h>
#include <hip/hip_bf16.h>
#include <cstdint>
#include <cstddef>

// Problem constants (B=4, S=4096, D=1024, DFF=4096, K_ACT=1024)
#define Bz 4
#define Sz 4096
#define Dz 1024
#define DFFz 4096
#define KACT 1024

typedef __bf16 bf16;
typedef __attribute__((ext_vector_type(8))) __bf16 bf16x8;
typedef __attribute__((ext_vector_type(4))) float f32x4;

__device__ __forceinline__ void async16(const void* g, void* l) {
  __builtin_amdgcn_global_load_lds(
      (const __attribute__((address_space(1))) void*)g,
      (__attribute__((address_space(3))) void*)l, 16, 0, 0);
}

// ---------------- zero output ----------------
__global__ void zero_out_k(float4* __restrict__ out, int n4) {
  int i = blockIdx.x * blockDim.x + threadIdx.x;
  int stride = gridDim.x * blockDim.x;
  for (; i < n4; i += stride) out[i] = make_float4(0.f, 0.f, 0.f, 0.f);
}

// ---------------- router: scores[b,s] = x[b,s,:]·rw + rb ----------------
__global__ void router_k(const float* __restrict__ x, const float* __restrict__ rw,
                         const float* __restrict__ rb, float* __restrict__ scores) {
  int row = blockIdx.x * 4 + (threadIdx.x >> 6);  // [0, B*S)
  int lane = threadIdx.x & 63;
  const float4* xr = (const float4*)(x + (size_t)row * Dz);
  const float4* wr = (const float4*)rw;
  float acc = 0.f;
#pragma unroll
  for (int i = 0; i < 4; ++i) {
    float4 a = xr[lane + i * 64];
    float4 w = wr[lane + i * 64];
    acc += a.x * w.x + a.y * w.y + a.z * w.z + a.w * w.w;
  }
#pragma unroll
  for (int d = 32; d; d >>= 1) acc += __shfl_down(acc, d, 64);
  if (lane == 0) scores[row] = acc + rb[0];
}

// ---------------- transpose + fp32->bf16 convert: out[C][R] = in[R][C] ----------------
__global__ void transpose_cvt(const float* __restrict__ in, bf16* __restrict__ out,
                              int R, int C) {
  __shared__ float t[32][33];
  int c0 = blockIdx.x * 32, r0 = blockIdx.y * 32;
  int tx = threadIdx.x, ty = threadIdx.y;  // (32, 8)
#pragma unroll
  for (int i = 0; i < 32; i += 8) t[ty + i][tx] = in[(size_t)(r0 + ty + i) * C + c0 + tx];
  __syncthreads();
#pragma unroll
  for (int i = 0; i < 32; i += 8)
    out[(size_t)(c0 + ty + i) * R + r0 + tx] = (bf16)t[tx][ty + i];
}

// ---------------- select top-K tokens per batch (rank by count), gather to bf16 ----------------
__global__ void select_gather_k(const float* __restrict__ x, const float* __restrict__ scores,
                                int* __restrict__ cnt, int* __restrict__ sel_idx,
                                float* __restrict__ gates, bf16* __restrict__ Xsel) {
  int b = blockIdx.x >> 12;     // S = 4096 = 2^12 blocks per batch row
  int s = blockIdx.x & (Sz - 1);
  const float* sc = scores + (size_t)b * Sz;
  float mine = sc[s];
  int tid = threadIdx.x;
  int c = 0;
  for (int t = tid; t < Sz; t += 256) {
    float o = sc[t];
    c += (o > mine) || (o == mine && t < s);  // matches top_k lowest-index tie-break
  }
#pragma unroll
  for (int d = 32; d; d >>= 1) c += __shfl_down(c, d, 64);
  __shared__ int red[4];
  __shared__ int rowbase;
  if ((tid & 63) == 0) red[tid >> 6] = c;
  __syncthreads();
  if (tid == 0) {
    int tot = red[0] + red[1] + red[2] + red[3];
    if (tot < KACT) {
      int pos = atomicAdd(cnt + b, 1);
      int m = b * KACT + pos;
      sel_idx[m] = s;
      gates[m] = 1.f / (1.f + expf(-mine));
      rowbase = m;
    } else {
      rowbase = -1;
    }
  }
  __syncthreads();
  int m = rowbase;
  if (m >= 0) {
    const float* xr = x + ((size_t)b * Sz + s) * Dz;
    bf16* xd = Xsel + (size_t)m * Dz;
    for (int i = tid; i < Dz; i += 256) xd[i] = (bf16)xr[i];
  }
}

// ---------------- GEMM1: H = gelu(Xsel @ w1 + b1), M=4096 N=4096 K=1024 ----------------
__global__ __launch_bounds__(256) void gemm1_k(const bf16* __restrict__ A,
                                               const bf16* __restrict__ Bt,
                                               const float* __restrict__ bias,
                                               bf16* __restrict__ H) {
  constexpr int K = Dz, N = DFFz;
  __shared__ __align__(16) bf16 As[128 * 32];
  __shared__ __align__(16) bf16 Bs[128 * 32];
  const int tid = threadIdx.x;
  const int wave = tid >> 6, lane = tid & 63;
  const int quad = lane >> 4, l16 = lane & 15;
  const int m0 = blockIdx.y * 128, n0 = blockIdx.x * 128;
  const int wm = (wave >> 1) * 64, wn = (wave & 1) * 64;
  const int r0 = tid >> 2;
  const int kk = (tid & 3) * 8;

  f32x4 acc[4][4] = {};

  const bf16* Ag = A + (size_t)(m0 + r0) * K + kk;
  const bf16* Bg = Bt + (size_t)(n0 + r0) * K + kk;
  bf16* lAs0 = &As[wave * 512];
  bf16* lAs1 = &As[2048 + wave * 512];
  bf16* lBs0 = &Bs[wave * 512];
  bf16* lBs1 = &Bs[2048 + wave * 512];

  for (int k0 = 0; k0 < K; k0 += 32) {
    async16(Ag + k0, lAs0);
    async16(Ag + (size_t)64 * K + k0, lAs1);
    async16(Bg + k0, lBs0);
    async16(Bg + (size_t)64 * K + k0, lBs1);
    __syncthreads();  // drains vmcnt before barrier (compiler-inserted)
    bf16x8 af[4], bfr[4];
#pragma unroll
    for (int i = 0; i < 4; ++i) {
      af[i] = *(const bf16x8*)&As[(wm + i * 16 + l16) * 32 + quad * 8];
      bfr[i] = *(const bf16x8*)&Bs[(wn + i * 16 + l16) * 32 + quad * 8];
    }
#pragma unroll
    for (int mi = 0; mi < 4; ++mi)
#pragma unroll
      for (int ni = 0; ni < 4; ++ni)
        acc[mi][ni] = __builtin_amdgcn_mfma_f32_16x16x32_bf16(af[mi], bfr[ni], acc[mi][ni], 0, 0, 0);
    __syncthreads();
  }

  // epilogue: bias + exact GELU -> bf16
#pragma unroll
  for (int mi = 0; mi < 4; ++mi) {
    int mbase = m0 + wm + mi * 16 + quad * 4;
#pragma unroll
    for (int ni = 0; ni < 4; ++ni) {
      int n = n0 + wn + ni * 16 + l16;
      float bn = bias[n];
#pragma unroll
      for (int r = 0; r < 4; ++r) {
        float z = acc[mi][ni][r] + bn;
        float g = 0.5f * z * (1.f + erff(z * 0.70710678118654752f));
        H[(size_t)(mbase + r) * N + n] = (bf16)g;
      }
    }
  }
}

// ---------------- GEMM2: out[sel] = (H @ w2 + b2) * gate, M=4096 N=1024 K=4096 ----------------
__global__ __launch_bounds__(256) void gemm2_k(const bf16* __restrict__ A,
                                               const bf16* __restrict__ Bt,
                                               const float* __restrict__ bias,
                                               const int* __restrict__ sel_idx,
                                               const float* __restrict__ gates,
                                               float* __restrict__ out) {
  constexpr int K = DFFz, N = Dz;
  __shared__ __align__(16) bf16 As[128 * 32];
  __shared__ __align__(16) bf16 Bs[128 * 32];
  const int tid = threadIdx.x;
  const int wave = tid >> 6, lane = tid & 63;
  const int quad = lane >> 4, l16 = lane & 15;
  const int m0 = blockIdx.y * 128, n0 = blockIdx.x * 128;
  const int wm = (wave >> 1) * 64, wn = (wave & 1) * 64;
  const int r0 = tid >> 2;
  const int kk = (tid & 3) * 8;

  f32x4 acc[4][4] = {};

  const bf16* Ag = A + (size_t)(m0 + r0) * K + kk;
  const bf16* Bg = Bt + (size_t)(n0 + r0) * K + kk;
  bf16* lAs0 = &As[wave * 512];
  bf16* lAs1 = &As[2048 + wave * 512];
  bf16* lBs0 = &Bs[wave * 512];
  bf16* lBs1 = &Bs[2048 + wave * 512];

  for (int k0 = 0; k0 < K; k0 += 32) {
    async16(Ag + k0, lAs0);
    async16(Ag + (size_t)64 * K + k0, lAs1);
    async16(Bg + k0, lBs0);
    async16(Bg + (size_t)64 * K + k0, lBs1);
    __syncthreads();
    bf16x8 af[4], bfr[4];
#pragma unroll
    for (int i = 0; i < 4; ++i) {
      af[i] = *(const bf16x8*)&As[(wm + i * 16 + l16) * 32 + quad * 8];
      bfr[i] = *(const bf16x8*)&Bs[(wn + i * 16 + l16) * 32 + quad * 8];
    }
#pragma unroll
    for (int mi = 0; mi < 4; ++mi)
#pragma unroll
      for (int ni = 0; ni < 4; ++ni)
        acc[mi][ni] = __builtin_amdgcn_mfma_f32_16x16x32_bf16(af[mi], bfr[ni], acc[mi][ni], 0, 0, 0);
    __syncthreads();
  }

  // epilogue: bias + sigmoid gate, scatter to out[b, sel_idx[m], :]
#pragma unroll
  for (int mi = 0; mi < 4; ++mi) {
#pragma unroll
    for (int r = 0; r < 4; ++r) {
      int m = m0 + wm + mi * 16 + quad * 4 + r;
      int b = m >> 10;  // KACT = 1024
      int s = sel_idx[m];
      float gt = gates[m];
      float* orow = out + ((size_t)b * Sz + s) * Dz;
#pragma unroll
      for (int ni = 0; ni < 4; ++ni) {
        int n = n0 + wn + ni * 16 + l16;
        orow[n] = (acc[mi][ni][r] + bias[n]) * gt;
      }
    }
  }
}

extern "C" void kernel_launch(void* const* d_in, const int* in_sizes, int n_in,
                              void* d_out, int out_size, void* d_ws, size_t ws_size,
                              hipStream_t stream) {
  (void)in_sizes; (void)n_in; (void)out_size; (void)ws_size;
  const float* x  = (const float*)d_in[0];
  const float* rw = (const float*)d_in[1];
  const float* rb = (const float*)d_in[2];
  const float* w1 = (const float*)d_in[3];
  const float* b1 = (const float*)d_in[4];
  const float* w2 = (const float*)d_in[5];
  const float* b2 = (const float*)d_in[6];
  float* out = (float*)d_out;

  char* ws = (char*)d_ws;
  float* scores = (float*)ws;  ws += (size_t)Bz * Sz * 4;          // 64 KB
  int*   sel_idx = (int*)ws;   ws += (size_t)Bz * KACT * 4;        // 16 KB
  float* gates = (float*)ws;   ws += (size_t)Bz * KACT * 4;        // 16 KB
  int*   cnt = (int*)ws;       ws += 256;
  bf16*  w1T = (bf16*)ws;      ws += (size_t)DFFz * Dz * 2;        // 8 MB  [4096][1024]
  bf16*  w2T = (bf16*)ws;      ws += (size_t)Dz * DFFz * 2;        // 8 MB  [1024][4096]
  bf16*  Xsel = (bf16*)ws;     ws += (size_t)Bz * KACT * Dz * 2;   // 8 MB  [4096][1024]
  bf16*  H = (bf16*)ws;        ws += (size_t)Bz * KACT * DFFz * 2; // 32 MB [4096][4096]

  hipMemsetAsync(cnt, 0, 16, stream);
  zero_out_k<<<8192, 256, 0, stream>>>((float4*)out, (Bz * Sz * Dz) / 4);
  router_k<<<(Bz * Sz) / 4, 256, 0, stream>>>(x, rw, rb, scores);
  transpose_cvt<<<dim3(DFFz / 32, Dz / 32), dim3(32, 8), 0, stream>>>(w1, w1T, Dz, DFFz);
  transpose_cvt<<<dim3(Dz / 32, DFFz / 32), dim3(32, 8), 0, stream>>>(w2, w2T, DFFz, Dz);
  select_gather_k<<<Bz * Sz, 256, 0, stream>>>(x, scores, cnt, sel_idx, gates, Xsel);
  gemm1_k<<<dim3(DFFz / 128, (Bz * KACT) / 128), 256, 0, stream>>>(Xsel, w1T, b1, H);
  gemm2_k<<<dim3(Dz / 128, (Bz * KACT) / 128), 256, 0, stream>>>(H, w2T, b2, sel_idx, gates, out);
}

// Round 2
// 352.367 us; speedup vs baseline: 1.0176x; 1.0176x over previous
//
#include <hip/hip_runtime.h>
#include <hip/hip_bf16.h>
#include <cstdint>
#include <cstddef>

// Problem constants (B=4, S=4096, D=1024, DFF=4096, K_ACT=1024)
#define Bz 4
#define Sz 4096
#define Dz 1024
#define DFFz 4096
#define KACT 1024

typedef __bf16 bf16;
typedef __attribute__((ext_vector_type(8))) __bf16 bf16x8;
typedef __attribute__((ext_vector_type(4))) __bf16 bf16x4;
typedef __attribute__((ext_vector_type(4))) float f32x4;

__device__ __forceinline__ void async16(const void* g, void* l) {
  __builtin_amdgcn_global_load_lds(
      (const __attribute__((address_space(1))) void*)g,
      (__attribute__((address_space(3))) void*)l, 16, 0, 0);
}

// ---------------- zero output ----------------
__global__ void zero_out_k(float4* __restrict__ out, int n4) {
  int i = blockIdx.x * blockDim.x + threadIdx.x;
  int stride = gridDim.x * blockDim.x;
  for (; i < n4; i += stride) out[i] = make_float4(0.f, 0.f, 0.f, 0.f);
}

// ---------------- router: scores[b,s] = x[b,s,:]·rw + rb ----------------
__global__ void router_k(const float* __restrict__ x, const float* __restrict__ rw,
                         const float* __restrict__ rb, float* __restrict__ scores) {
  int row = blockIdx.x * 4 + (threadIdx.x >> 6);  // [0, B*S)
  int lane = threadIdx.x & 63;
  const float4* xr = (const float4*)(x + (size_t)row * Dz);
  const float4* wr = (const float4*)rw;
  float acc = 0.f;
#pragma unroll
  for (int i = 0; i < 4; ++i) {
    float4 a = xr[lane + i * 64];
    float4 w = wr[lane + i * 64];
    acc += a.x * w.x + a.y * w.y + a.z * w.z + a.w * w.w;
  }
#pragma unroll
  for (int d = 32; d; d >>= 1) acc += __shfl_down(acc, d, 64);
  if (lane == 0) scores[row] = acc + rb[0];
}

// ---------------- transpose + fp32->bf16 convert: out[C][R] = in[R][C] ----------------
__global__ void transpose_cvt(const float* __restrict__ in, bf16* __restrict__ out,
                              int R, int C) {
  __shared__ float t[32][33];
  int c0 = blockIdx.x * 32, r0 = blockIdx.y * 32;
  int tx = threadIdx.x, ty = threadIdx.y;  // (32, 8)
#pragma unroll
  for (int i = 0; i < 32; i += 8) t[ty + i][tx] = in[(size_t)(r0 + ty + i) * C + c0 + tx];
  __syncthreads();
#pragma unroll
  for (int i = 0; i < 32; i += 8)
    out[(size_t)(c0 + ty + i) * R + r0 + tx] = (bf16)t[tx][ty + i];
}

// ---- select top-K per batch: position = rank (strict total order), NO atomics ----
__global__ void select_gather_k(const float* __restrict__ x, const float* __restrict__ scores,
                                int* __restrict__ sel_idx, float* __restrict__ gates,
                                bf16* __restrict__ Xsel) {
  int b = blockIdx.x >> 12;     // S = 4096 = 2^12 blocks per batch row
  int s = blockIdx.x & (Sz - 1);
  const float* sc = scores + (size_t)b * Sz;
  float mine = sc[s];
  int tid = threadIdx.x;
  int c = 0;
  for (int t = tid; t < Sz; t += 256) {
    float o = sc[t];
    c += (o > mine) || (o == mine && t < s);  // matches top_k lowest-index tie-break
  }
#pragma unroll
  for (int d = 32; d; d >>= 1) c += __shfl_down(c, d, 64);
  __shared__ int red[4];
  if ((tid & 63) == 0) red[tid >> 6] = c;
  __syncthreads();
  int tot = red[0] + red[1] + red[2] + red[3];  // rank of token s within batch b
  if (tot >= KACT) return;                      // not selected
  int m = b * KACT + tot;                       // unique compacted slot (== top_k order)
  if (tid == 0) {
    sel_idx[m] = s;
    gates[m] = 1.f / (1.f + expf(-mine));
  }
  const float4* xr = (const float4*)(x + ((size_t)b * Sz + s) * Dz);
  bf16x4* xd = (bf16x4*)(Xsel + (size_t)m * Dz);
  float4 v = xr[tid];  // 256 threads * 4 = 1024 = Dz
  bf16x4 o = {(bf16)v.x, (bf16)v.y, (bf16)v.z, (bf16)v.w};
  xd[tid] = o;
}

// ======== double-buffered 128x128 MFMA GEMM body (C = A[M,K] @ Bt[N,K]^T) ========
// raw s_waitcnt vmcnt(4) + s_barrier: loads for tile k+1 stay in flight during
// compute of tile k (compiler's __syncthreads would drain vmcnt(0) -> 1-block/CU stall).
#define GEMM_PREAMBLE(KV)                                                  \
  __shared__ __align__(16) bf16 As[2][128 * 32];                           \
  __shared__ __align__(16) bf16 Bs[2][128 * 32];                           \
  const int tid = threadIdx.x;                                             \
  const int wave = tid >> 6, lane = tid & 63;                              \
  const int quad = lane >> 4, l16 = lane & 15;                             \
  const int m0 = blockIdx.y * 128, n0 = blockIdx.x * 128;                  \
  const int wm = (wave >> 1) * 64, wn = (wave & 1) * 64;                   \
  const int r0 = tid >> 2;                                                 \
  const int kk = (tid & 3) * 8;                                            \
  f32x4 acc[4][4] = {};                                                    \
  const bf16* Ag = A + (size_t)(m0 + r0) * KV + kk;                        \
  const bf16* Bg = Bt + (size_t)(n0 + r0) * KV + kk;                       \
  const int ldsoff = wave * 512;

#define GEMM_ISSUE(KV, p, k0)                                              \
  async16(Ag + (k0), &As[p][ldsoff]);                                      \
  async16(Ag + (size_t)64 * KV + (k0), &As[p][2048 + ldsoff]);             \
  async16(Bg + (k0), &Bs[p][ldsoff]);                                      \
  async16(Bg + (size_t)64 * KV + (k0), &Bs[p][2048 + ldsoff]);

#define GEMM_MAINLOOP(KV)                                                  \
  GEMM_ISSUE(KV, 0, 0)                                                     \
  int cur = 0;                                                             \
  for (int it = 0; it < (KV) / 32; ++it) {                                 \
    if (it + 1 < (KV) / 32) {                                              \
      GEMM_ISSUE(KV, cur ^ 1, (it + 1) * 32)                               \
      asm volatile("s_waitcnt vmcnt(4)\ns_barrier" ::: "memory");          \
    } else {                                                               \
      asm volatile("s_waitcnt vmcnt(0)\ns_barrier" ::: "memory");          \
    }                                                                      \
    bf16x8 af[4], bfr[4];                                                  \
    _Pragma("unroll")                                                      \
    for (int i = 0; i < 4; ++i) {                                          \
      af[i] = *(const bf16x8*)&As[cur][(wm + i * 16 + l16) * 32 + quad * 8]; \
      bfr[i] = *(const bf16x8*)&Bs[cur][(wn + i * 16 + l16) * 32 + quad * 8]; \
    }                                                                      \
    _Pragma("unroll")                                                      \
    for (int mi = 0; mi < 4; ++mi)                                         \
      _Pragma("unroll")                                                    \
      for (int ni = 0; ni < 4; ++ni)                                       \
        acc[mi][ni] = __builtin_amdgcn_mfma_f32_16x16x32_bf16(af[mi], bfr[ni], acc[mi][ni], 0, 0, 0); \
    asm volatile("s_waitcnt lgkmcnt(0)\ns_barrier" ::: "memory");          \
    cur ^= 1;                                                              \
  }

// ---------------- GEMM1: H = gelu(Xsel @ w1 + b1), M=4096 N=4096 K=1024 ----------------
__global__ __launch_bounds__(256) void gemm1_k(const bf16* __restrict__ A,
                                               const bf16* __restrict__ Bt,
                                               const float* __restrict__ bias,
                                               bf16* __restrict__ H) {
  constexpr int K = Dz, N = DFFz;
  GEMM_PREAMBLE(K)
  GEMM_MAINLOOP(K)
  // epilogue: bias + exact GELU -> bf16   (C/D layout: col=lane&15, row=quad*4+reg)
#pragma unroll
  for (int mi = 0; mi < 4; ++mi) {
    int mbase = m0 + wm + mi * 16 + quad * 4;
#pragma unroll
    for (int ni = 0; ni < 4; ++ni) {
      int n = n0 + wn + ni * 16 + l16;
      float bn = bias[n];
#pragma unroll
      for (int r = 0; r < 4; ++r) {
        float z = acc[mi][ni][r] + bn;
        float g = 0.5f * z * (1.f + erff(z * 0.70710678118654752f));
        H[(size_t)(mbase + r) * N + n] = (bf16)g;
      }
    }
  }
}

// ---------------- GEMM2: out[sel] = (H @ w2 + b2) * gate, M=4096 N=1024 K=4096 ----------------
__global__ __launch_bounds__(256) void gemm2_k(const bf16* __restrict__ A,
                                               const bf16* __restrict__ Bt,
                                               const float* __restrict__ bias,
                                               const int* __restrict__ sel_idx,
                                               const float* __restrict__ gates,
                                               float* __restrict__ out) {
  constexpr int K = DFFz;
  GEMM_PREAMBLE(K)
  GEMM_MAINLOOP(K)
  // epilogue: bias + sigmoid gate, scatter to out[b, sel_idx[m], :]
#pragma unroll
  for (int mi = 0; mi < 4; ++mi) {
#pragma unroll
    for (int r = 0; r < 4; ++r) {
      int m = m0 + wm + mi * 16 + quad * 4 + r;
      int b = m >> 10;  // KACT = 1024
      int s = sel_idx[m];
      float gt = gates[m];
      float* orow = out + ((size_t)b * Sz + s) * Dz;
#pragma unroll
      for (int ni = 0; ni < 4; ++ni) {
        int n = n0 + wn + ni * 16 + l16;
        orow[n] = (acc[mi][ni][r] + bias[n]) * gt;
      }
    }
  }
}

extern "C" void kernel_launch(void* const* d_in, const int* in_sizes, int n_in,
                              void* d_out, int out_size, void* d_ws, size_t ws_size,
                              hipStream_t stream) {
  (void)in_sizes; (void)n_in; (void)out_size; (void)ws_size;
  const float* x  = (const float*)d_in[0];
  const float* rw = (const float*)d_in[1];
  const float* rb = (const float*)d_in[2];
  const float* w1 = (const float*)d_in[3];
  const float* b1 = (const float*)d_in[4];
  const float* w2 = (const float*)d_in[5];
  const float* b2 = (const float*)d_in[6];
  float* out = (float*)d_out;

  char* ws = (char*)d_ws;
  float* scores = (float*)ws;  ws += (size_t)Bz * Sz * 4;          // 64 KB
  int*   sel_idx = (int*)ws;   ws += (size_t)Bz * KACT * 4;        // 16 KB
  float* gates = (float*)ws;   ws += (size_t)Bz * KACT * 4;        // 16 KB
  bf16*  w1T = (bf16*)ws;      ws += (size_t)DFFz * Dz * 2;        // 8 MB  [4096][1024]
  bf16*  w2T = (bf16*)ws;      ws += (size_t)Dz * DFFz * 2;        // 8 MB  [1024][4096]
  bf16*  Xsel = (bf16*)ws;     ws += (size_t)Bz * KACT * Dz * 2;   // 8 MB  [4096][1024]
  bf16*  H = (bf16*)ws;        ws += (size_t)Bz * KACT * DFFz * 2; // 32 MB [4096][4096]

  zero_out_k<<<8192, 256, 0, stream>>>((float4*)out, (Bz * Sz * Dz) / 4);
  router_k<<<(Bz * Sz) / 4, 256, 0, stream>>>(x, rw, rb, scores);
  transpose_cvt<<<dim3(DFFz / 32, Dz / 32), dim3(32, 8), 0, stream>>>(w1, w1T, Dz, DFFz);
  transpose_cvt<<<dim3(Dz / 32, DFFz / 32), dim3(32, 8), 0, stream>>>(w2, w2T, DFFz, Dz);
  select_gather_k<<<Bz * Sz, 256, 0, stream>>>(x, scores, sel_idx, gates, Xsel);
  gemm1_k<<<dim3(DFFz / 128, (Bz * KACT) / 128), 256, 0, stream>>>(Xsel, w1T, b1, H);
  gemm2_k<<<dim3(Dz / 128, (Bz * KACT) / 128), 256, 0, stream>>>(H, w2T, b2, sel_idx, gates, out);
}

// Round 3
// 344.294 us; speedup vs baseline: 1.0414x; 1.0234x over previous
//
#include <hip/hip_runtime.h>
#include <hip/hip_bf16.h>
#include <cstdint>
#include <cstddef>

// Problem constants (B=4, S=4096, D=1024, DFF=4096, K_ACT=1024)
#define Bz 4
#define Sz 4096
#define Dz 1024
#define DFFz 4096
#define KACT 1024

typedef __bf16 bf16;
typedef __attribute__((ext_vector_type(8))) __bf16 bf16x8;
typedef __attribute__((ext_vector_type(4))) __bf16 bf16x4;
typedef __attribute__((ext_vector_type(4))) float f32x4;

__device__ __forceinline__ void async16(const void* g, void* l) {
  __builtin_amdgcn_global_load_lds(
      (const __attribute__((address_space(1))) void*)g,
      (__attribute__((address_space(3))) void*)l, 16, 0, 0);
}

// ---------------- zero output ----------------
__global__ void zero_out_k(float4* __restrict__ out, int n4) {
  int i = blockIdx.x * blockDim.x + threadIdx.x;
  int stride = gridDim.x * blockDim.x;
  for (; i < n4; i += stride) out[i] = make_float4(0.f, 0.f, 0.f, 0.f);
}

// ---------------- router: scores[b,s] = x[b,s,:]·rw + rb ----------------
__global__ void router_k(const float* __restrict__ x, const float* __restrict__ rw,
                         const float* __restrict__ rb, float* __restrict__ scores) {
  int row = blockIdx.x * 4 + (threadIdx.x >> 6);  // [0, B*S)
  int lane = threadIdx.x & 63;
  const float4* xr = (const float4*)(x + (size_t)row * Dz);
  const float4* wr = (const float4*)rw;
  float acc = 0.f;
#pragma unroll
  for (int i = 0; i < 4; ++i) {
    float4 a = xr[lane + i * 64];
    float4 w = wr[lane + i * 64];
    acc += a.x * w.x + a.y * w.y + a.z * w.z + a.w * w.w;
  }
#pragma unroll
  for (int d = 32; d; d >>= 1) acc += __shfl_down(acc, d, 64);
  if (lane == 0) scores[row] = acc + rb[0];
}

// ---------------- transpose + fp32->bf16 convert: out[C][R] = in[R][C] ----------------
__global__ void transpose_cvt(const float* __restrict__ in, bf16* __restrict__ out,
                              int R, int C) {
  __shared__ float t[32][33];
  int c0 = blockIdx.x * 32, r0 = blockIdx.y * 32;
  int tx = threadIdx.x, ty = threadIdx.y;  // (32, 8)
#pragma unroll
  for (int i = 0; i < 32; i += 8) t[ty + i][tx] = in[(size_t)(r0 + ty + i) * C + c0 + tx];
  __syncthreads();
#pragma unroll
  for (int i = 0; i < 32; i += 8)
    out[(size_t)(c0 + ty + i) * R + r0 + tx] = (bf16)t[tx][ty + i];
}

// ---- select top-K per batch: position = rank (strict total order), NO atomics ----
__global__ void select_gather_k(const float* __restrict__ x, const float* __restrict__ scores,
                                int* __restrict__ sel_idx, float* __restrict__ gates,
                                bf16* __restrict__ Xsel) {
  int b = blockIdx.x >> 12;     // S = 4096 = 2^12 blocks per batch row
  int s = blockIdx.x & (Sz - 1);
  const float* sc = scores + (size_t)b * Sz;
  float mine = sc[s];
  int tid = threadIdx.x;
  int c = 0;
  for (int t = tid; t < Sz; t += 256) {
    float o = sc[t];
    c += (o > mine) || (o == mine && t < s);  // matches top_k lowest-index tie-break
  }
#pragma unroll
  for (int d = 32; d; d >>= 1) c += __shfl_down(c, d, 64);
  __shared__ int red[4];
  if ((tid & 63) == 0) red[tid >> 6] = c;
  __syncthreads();
  int tot = red[0] + red[1] + red[2] + red[3];  // rank of token s within batch b
  if (tot >= KACT) return;                      // not selected
  int m = b * KACT + tot;                       // unique compacted slot (== top_k order)
  if (tid == 0) {
    sel_idx[m] = s;
    gates[m] = 1.f / (1.f + expf(-mine));
  }
  const float4* xr = (const float4*)(x + ((size_t)b * Sz + s) * Dz);
  bf16x4* xd = (bf16x4*)(Xsel + (size_t)m * Dz);
  float4 v = xr[tid];  // 256 threads * 4 = 1024 = Dz
  bf16x4 o = {(bf16)v.x, (bf16)v.y, (bf16)v.z, (bf16)v.w};
  xd[tid] = o;
}

// ---------------- GEMM1: H = gelu(Xsel @ w1 + b1), M=4096 N=4096 K=1024 ----------------
// R1-proven structure: single-buffer LDS, compiler-scheduled __syncthreads.
__global__ __launch_bounds__(256) void gemm1_k(const bf16* __restrict__ A,
                                               const bf16* __restrict__ Bt,
                                               const float* __restrict__ bias,
                                               bf16* __restrict__ H) {
  constexpr int K = Dz, N = DFFz;
  __shared__ __align__(16) bf16 As[128 * 32];
  __shared__ __align__(16) bf16 Bs[128 * 32];
  const int tid = threadIdx.x;
  const int wave = tid >> 6, lane = tid & 63;
  const int quad = lane >> 4, l16 = lane & 15;
  const int m0 = blockIdx.y * 128, n0 = blockIdx.x * 128;
  const int wm = (wave >> 1) * 64, wn = (wave & 1) * 64;
  const int r0 = tid >> 2;
  const int kk = (tid & 3) * 8;

  f32x4 acc[4][4] = {};

  const bf16* Ag = A + (size_t)(m0 + r0) * K + kk;
  const bf16* Bg = Bt + (size_t)(n0 + r0) * K + kk;
  bf16* lAs0 = &As[wave * 512];
  bf16* lAs1 = &As[2048 + wave * 512];
  bf16* lBs0 = &Bs[wave * 512];
  bf16* lBs1 = &Bs[2048 + wave * 512];

  for (int k0 = 0; k0 < K; k0 += 32) {
    async16(Ag + k0, lAs0);
    async16(Ag + (size_t)64 * K + k0, lAs1);
    async16(Bg + k0, lBs0);
    async16(Bg + (size_t)64 * K + k0, lBs1);
    __syncthreads();
    bf16x8 af[4], bfr[4];
#pragma unroll
    for (int i = 0; i < 4; ++i) {
      af[i] = *(const bf16x8*)&As[(wm + i * 16 + l16) * 32 + quad * 8];
      bfr[i] = *(const bf16x8*)&Bs[(wn + i * 16 + l16) * 32 + quad * 8];
    }
#pragma unroll
    for (int mi = 0; mi < 4; ++mi)
#pragma unroll
      for (int ni = 0; ni < 4; ++ni)
        acc[mi][ni] = __builtin_amdgcn_mfma_f32_16x16x32_bf16(af[mi], bfr[ni], acc[mi][ni], 0, 0, 0);
    __syncthreads();
  }

  // epilogue: bias + exact GELU -> bf16   (C/D layout: col=lane&15, row=quad*4+reg)
#pragma unroll
  for (int mi = 0; mi < 4; ++mi) {
    int mbase = m0 + wm + mi * 16 + quad * 4;
#pragma unroll
    for (int ni = 0; ni < 4; ++ni) {
      int n = n0 + wn + ni * 16 + l16;
      float bn = bias[n];
#pragma unroll
      for (int r = 0; r < 4; ++r) {
        float z = acc[mi][ni][r] + bn;
        float g = 0.5f * z * (1.f + erff(z * 0.70710678118654752f));
        H[(size_t)(mbase + r) * N + n] = (bf16)g;
      }
    }
  }
}

// ---- GEMM2 split-K: out[sel] += (H @ w2)_chunk * gate (+ bias*gate on chunk 0) ----
// M=4096 N=1024 K=4096, split into 4 chunks of 1024 -> 1024 blocks (4/CU) vs 256 (1/CU).
__global__ __launch_bounds__(256) void gemm2_k(const bf16* __restrict__ A,
                                               const bf16* __restrict__ Bt,
                                               const float* __restrict__ bias,
                                               const int* __restrict__ sel_idx,
                                               const float* __restrict__ gates,
                                               float* __restrict__ out) {
  constexpr int K = DFFz;
  constexpr int KCH = 1024;  // chunk length
  __shared__ __align__(16) bf16 As[128 * 32];
  __shared__ __align__(16) bf16 Bs[128 * 32];
  const int tid = threadIdx.x;
  const int wave = tid >> 6, lane = tid & 63;
  const int quad = lane >> 4, l16 = lane & 15;
  const int m0 = blockIdx.y * 128, n0 = blockIdx.x * 128;
  const int kc0 = blockIdx.z * KCH;
  const int wm = (wave >> 1) * 64, wn = (wave & 1) * 64;
  const int r0 = tid >> 2;
  const int kk = (tid & 3) * 8;

  f32x4 acc[4][4] = {};

  const bf16* Ag = A + (size_t)(m0 + r0) * K + kc0 + kk;
  const bf16* Bg = Bt + (size_t)(n0 + r0) * K + kc0 + kk;
  bf16* lAs0 = &As[wave * 512];
  bf16* lAs1 = &As[2048 + wave * 512];
  bf16* lBs0 = &Bs[wave * 512];
  bf16* lBs1 = &Bs[2048 + wave * 512];

  for (int k0 = 0; k0 < KCH; k0 += 32) {
    async16(Ag + k0, lAs0);
    async16(Ag + (size_t)64 * K + k0, lAs1);
    async16(Bg + k0, lBs0);
    async16(Bg + (size_t)64 * K + k0, lBs1);
    __syncthreads();
    bf16x8 af[4], bfr[4];
#pragma unroll
    for (int i = 0; i < 4; ++i) {
      af[i] = *(const bf16x8*)&As[(wm + i * 16 + l16) * 32 + quad * 8];
      bfr[i] = *(const bf16x8*)&Bs[(wn + i * 16 + l16) * 32 + quad * 8];
    }
#pragma unroll
    for (int mi = 0; mi < 4; ++mi)
#pragma unroll
      for (int ni = 0; ni < 4; ++ni)
        acc[mi][ni] = __builtin_amdgcn_mfma_f32_16x16x32_bf16(af[mi], bfr[ni], acc[mi][ni], 0, 0, 0);
    __syncthreads();
  }

  // epilogue: atomic accumulate (out pre-zeroed); chunk 0 also adds bias*gate
  const bool addbias = (blockIdx.z == 0);
#pragma unroll
  for (int mi = 0; mi < 4; ++mi) {
#pragma unroll
    for (int r = 0; r < 4; ++r) {
      int m = m0 + wm + mi * 16 + quad * 4 + r;
      int b = m >> 10;  // KACT = 1024
      int s = sel_idx[m];
      float gt = gates[m];
      float* orow = out + ((size_t)b * Sz + s) * Dz;
#pragma unroll
      for (int ni = 0; ni < 4; ++ni) {
        int n = n0 + wn + ni * 16 + l16;
        float v = acc[mi][ni][r] * gt;
        if (addbias) v += bias[n] * gt;
        atomicAdd(&orow[n], v);
      }
    }
  }
}

extern "C" void kernel_launch(void* const* d_in, const int* in_sizes, int n_in,
                              void* d_out, int out_size, void* d_ws, size_t ws_size,
                              hipStream_t stream) {
  (void)in_sizes; (void)n_in; (void)out_size; (void)ws_size;
  const float* x  = (const float*)d_in[0];
  const float* rw = (const float*)d_in[1];
  const float* rb = (const float*)d_in[2];
  const float* w1 = (const float*)d_in[3];
  const float* b1 = (const float*)d_in[4];
  const float* w2 = (const float*)d_in[5];
  const float* b2 = (const float*)d_in[6];
  float* out = (float*)d_out;

  char* ws = (char*)d_ws;
  float* scores = (float*)ws;  ws += (size_t)Bz * Sz * 4;          // 64 KB
  int*   sel_idx = (int*)ws;   ws += (size_t)Bz * KACT * 4;        // 16 KB
  float* gates = (float*)ws;   ws += (size_t)Bz * KACT * 4;        // 16 KB
  bf16*  w1T = (bf16*)ws;      ws += (size_t)DFFz * Dz * 2;        // 8 MB  [4096][1024]
  bf16*  w2T = (bf16*)ws;      ws += (size_t)Dz * DFFz * 2;        // 8 MB  [1024][4096]
  bf16*  Xsel = (bf16*)ws;     ws += (size_t)Bz * KACT * Dz * 2;   // 8 MB  [4096][1024]
  bf16*  H = (bf16*)ws;        ws += (size_t)Bz * KACT * DFFz * 2; // 32 MB [4096][4096]

  zero_out_k<<<8192, 256, 0, stream>>>((float4*)out, (Bz * Sz * Dz) / 4);
  router_k<<<(Bz * Sz) / 4, 256, 0, stream>>>(x, rw, rb, scores);
  transpose_cvt<<<dim3(DFFz / 32, Dz / 32), dim3(32, 8), 0, stream>>>(w1, w1T, Dz, DFFz);
  transpose_cvt<<<dim3(Dz / 32, DFFz / 32), dim3(32, 8), 0, stream>>>(w2, w2T, DFFz, Dz);
  select_gather_k<<<Bz * Sz, 256, 0, stream>>>(x, scores, sel_idx, gates, Xsel);
  gemm1_k<<<dim3(DFFz / 128, (Bz * KACT) / 128), 256, 0, stream>>>(Xsel, w1T, b1, H);
  gemm2_k<<<dim3(Dz / 128, (Bz * KACT) / 128, 4), 256, 0, stream>>>(H, w2T, b2, sel_idx, gates, out);
}

// Round 4
// 315.261 us; speedup vs baseline: 1.1373x; 1.0921x over previous
//
#include <hip/hip_runtime.h>
#include <hip/hip_bf16.h>
#include <cstdint>
#include <cstddef>

// Problem constants (B=4, S=4096, D=1024, DFF=4096, K_ACT=1024)
#define Bz 4
#define Sz 4096
#define Dz 1024
#define DFFz 4096
#define KACT 1024

typedef __bf16 bf16;
typedef __attribute__((ext_vector_type(8))) __bf16 bf16x8;
typedef __attribute__((ext_vector_type(4))) __bf16 bf16x4;
typedef __attribute__((ext_vector_type(4))) float f32x4;

__device__ __forceinline__ void async16(const void* g, void* l) {
  __builtin_amdgcn_global_load_lds(
      (const __attribute__((address_space(1))) void*)g,
      (__attribute__((address_space(3))) void*)l, 16, 0, 0);
}

// ---- router + zero: scores[b,s] = x[b,s,:]·rw + rb; also zero out rows ----
__global__ void router_k(const float* __restrict__ x, const float* __restrict__ rw,
                         const float* __restrict__ rb, float* __restrict__ scores,
                         float4* __restrict__ out4) {
  int row = blockIdx.x * 4 + (threadIdx.x >> 6);  // [0, B*S)
  int lane = threadIdx.x & 63;
  const float4* xr = (const float4*)(x + (size_t)row * Dz);
  const float4* wr = (const float4*)rw;
  float acc = 0.f;
#pragma unroll
  for (int i = 0; i < 4; ++i) {
    float4 a = xr[lane + i * 64];
    float4 w = wr[lane + i * 64];
    acc += a.x * w.x + a.y * w.y + a.z * w.z + a.w * w.w;
  }
#pragma unroll
  for (int d = 32; d; d >>= 1) acc += __shfl_down(acc, d, 64);
  if (lane == 0) scores[row] = acc + rb[0];
  // zero the 4 output rows this block covers (4096 float4 / 256 threads)
  float4* o = out4 + (size_t)blockIdx.x * 4 * (Dz / 4);
  const float4 z = make_float4(0.f, 0.f, 0.f, 0.f);
#pragma unroll
  for (int i = 0; i < 4; ++i) o[threadIdx.x + i * 256] = z;
}

// ---------------- transpose + fp32->bf16 convert: out[C][R] = in[R][C] ----------------
__global__ void transpose_cvt(const float* __restrict__ in, bf16* __restrict__ out,
                              int R, int C) {
  __shared__ float t[32][33];
  int c0 = blockIdx.x * 32, r0 = blockIdx.y * 32;
  int tx = threadIdx.x, ty = threadIdx.y;  // (32, 8)
#pragma unroll
  for (int i = 0; i < 32; i += 8) t[ty + i][tx] = in[(size_t)(r0 + ty + i) * C + c0 + tx];
  __syncthreads();
#pragma unroll
  for (int i = 0; i < 32; i += 8)
    out[(size_t)(c0 + ty + i) * R + r0 + tx] = (bf16)t[tx][ty + i];
}

// ---- select top-K per batch, 16 tokens/block: scores staged in LDS once ----
__global__ __launch_bounds__(256) void select_gather_k(
    const float* __restrict__ x, const float* __restrict__ scores,
    int* __restrict__ sel_idx, float* __restrict__ gates, bf16* __restrict__ Xsel) {
  int b = blockIdx.x >> 8;            // 256 blocks per batch row
  int s0 = (blockIdx.x & 255) * 16;   // first of 16 tokens
  __shared__ float sc[Sz];
  __shared__ int red[16][4];
  __shared__ int rk[16];
  const int tid = threadIdx.x;
  const int wave = tid >> 6, lane = tid & 63;
  const float* srow = scores + (size_t)b * Sz;
#pragma unroll
  for (int i = 0; i < 4; ++i)
    ((float4*)sc)[tid + i * 256] = ((const float4*)srow)[tid + i * 256];
  __syncthreads();
  float mine[16];
#pragma unroll
  for (int j = 0; j < 16; ++j) mine[j] = sc[s0 + j];
  int cnt[16] = {};
  for (int t = tid; t < Sz; t += 256) {
    float o = sc[t];
#pragma unroll
    for (int j = 0; j < 16; ++j)
      cnt[j] += (o > mine[j]) || (o == mine[j] && t < s0 + j);
  }
#pragma unroll
  for (int j = 0; j < 16; ++j) {
    int c = cnt[j];
#pragma unroll
    for (int d = 32; d; d >>= 1) c += __shfl_down(c, d, 64);
    if (lane == 0) red[j][wave] = c;
  }
  __syncthreads();
  if (tid < 16) {
    int rank = red[tid][0] + red[tid][1] + red[tid][2] + red[tid][3];
    rk[tid] = rank;
    if (rank < KACT) {
      int m = b * KACT + rank;
      sel_idx[m] = s0 + tid;
      gates[m] = 1.f / (1.f + expf(-sc[s0 + tid]));
    }
  }
  __syncthreads();
#pragma unroll
  for (int j = 0; j < 16; ++j) {
    int rank = rk[j];
    if (rank >= KACT) continue;
    int m = b * KACT + rank;
    float4 v = ((const float4*)(x + ((size_t)b * Sz + s0 + j) * Dz))[tid];
    bf16x4 o = {(bf16)v.x, (bf16)v.y, (bf16)v.z, (bf16)v.w};
    ((bf16x4*)(Xsel + (size_t)m * Dz))[tid] = o;
  }
}

// ---------------- GEMM1: H = gelu(Xsel @ w1 + b1), M=4096 N=4096 K=1024 ----------------
// R1-proven structure: single-buffer LDS, compiler-scheduled __syncthreads, 128x128.
__global__ __launch_bounds__(256) void gemm1_k(const bf16* __restrict__ A,
                                               const bf16* __restrict__ Bt,
                                               const float* __restrict__ bias,
                                               bf16* __restrict__ H) {
  constexpr int K = Dz, N = DFFz;
  __shared__ __align__(16) bf16 As[128 * 32];
  __shared__ __align__(16) bf16 Bs[128 * 32];
  const int tid = threadIdx.x;
  const int wave = tid >> 6, lane = tid & 63;
  const int quad = lane >> 4, l16 = lane & 15;
  const int m0 = blockIdx.y * 128, n0 = blockIdx.x * 128;
  const int wm = (wave >> 1) * 64, wn = (wave & 1) * 64;
  const int r0 = tid >> 2;
  const int kk = (tid & 3) * 8;

  f32x4 acc[4][4] = {};

  const bf16* Ag = A + (size_t)(m0 + r0) * K + kk;
  const bf16* Bg = Bt + (size_t)(n0 + r0) * K + kk;
  bf16* lAs0 = &As[wave * 512];
  bf16* lAs1 = &As[2048 + wave * 512];
  bf16* lBs0 = &Bs[wave * 512];
  bf16* lBs1 = &Bs[2048 + wave * 512];

  for (int k0 = 0; k0 < K; k0 += 32) {
    async16(Ag + k0, lAs0);
    async16(Ag + (size_t)64 * K + k0, lAs1);
    async16(Bg + k0, lBs0);
    async16(Bg + (size_t)64 * K + k0, lBs1);
    __syncthreads();
    bf16x8 af[4], bfr[4];
#pragma unroll
    for (int i = 0; i < 4; ++i) {
      af[i] = *(const bf16x8*)&As[(wm + i * 16 + l16) * 32 + quad * 8];
      bfr[i] = *(const bf16x8*)&Bs[(wn + i * 16 + l16) * 32 + quad * 8];
    }
#pragma unroll
    for (int mi = 0; mi < 4; ++mi)
#pragma unroll
      for (int ni = 0; ni < 4; ++ni)
        acc[mi][ni] = __builtin_amdgcn_mfma_f32_16x16x32_bf16(af[mi], bfr[ni], acc[mi][ni], 0, 0, 0);
    __syncthreads();
  }

  // epilogue: bias + exact GELU -> bf16   (C/D layout: col=lane&15, row=quad*4+reg)
#pragma unroll
  for (int mi = 0; mi < 4; ++mi) {
    int mbase = m0 + wm + mi * 16 + quad * 4;
#pragma unroll
    for (int ni = 0; ni < 4; ++ni) {
      int n = n0 + wn + ni * 16 + l16;
      float bn = bias[n];
#pragma unroll
      for (int r = 0; r < 4; ++r) {
        float z = acc[mi][ni][r] + bn;
        float g = 0.5f * z * (1.f + erff(z * 0.70710678118654752f));
        H[(size_t)(mbase + r) * N + n] = (bf16)g;
      }
    }
  }
}

// ---- GEMM2: out[sel] = (H @ w2 + b2) * gate; 128m x 64n tiles -> 512 blocks (2/CU) ----
__global__ __launch_bounds__(256) void gemm2_k(const bf16* __restrict__ A,
                                               const bf16* __restrict__ Bt,
                                               const float* __restrict__ bias,
                                               const int* __restrict__ sel_idx,
                                               const float* __restrict__ gates,
                                               float* __restrict__ out) {
  constexpr int K = DFFz;
  __shared__ __align__(16) bf16 As[128 * 32];  // 8 KB
  __shared__ __align__(16) bf16 Bs[64 * 32];   // 4 KB
  const int tid = threadIdx.x;
  const int wave = tid >> 6, lane = tid & 63;
  const int quad = lane >> 4, l16 = lane & 15;
  const int m0 = blockIdx.y * 128, n0 = blockIdx.x * 64;
  const int wm = (wave >> 1) * 64, wn = (wave & 1) * 32;
  const int r0 = tid >> 2;
  const int kk = (tid & 3) * 8;

  f32x4 acc[4][2] = {};

  const bf16* Ag = A + (size_t)(m0 + r0) * K + kk;
  const bf16* Bg = Bt + (size_t)(n0 + r0) * K + kk;
  bf16* lAs0 = &As[wave * 512];
  bf16* lAs1 = &As[2048 + wave * 512];
  bf16* lBs0 = &Bs[wave * 512];

  for (int k0 = 0; k0 < K; k0 += 32) {
    async16(Ag + k0, lAs0);
    async16(Ag + (size_t)64 * K + k0, lAs1);
    async16(Bg + k0, lBs0);
    __syncthreads();
    bf16x8 af[4], bfr[2];
#pragma unroll
    for (int i = 0; i < 4; ++i)
      af[i] = *(const bf16x8*)&As[(wm + i * 16 + l16) * 32 + quad * 8];
#pragma unroll
    for (int j = 0; j < 2; ++j)
      bfr[j] = *(const bf16x8*)&Bs[(wn + j * 16 + l16) * 32 + quad * 8];
#pragma unroll
    for (int mi = 0; mi < 4; ++mi)
#pragma unroll
      for (int ni = 0; ni < 2; ++ni)
        acc[mi][ni] = __builtin_amdgcn_mfma_f32_16x16x32_bf16(af[mi], bfr[ni], acc[mi][ni], 0, 0, 0);
    __syncthreads();
  }

  // epilogue: bias + sigmoid gate, direct scatter (out rows pre-zeroed by router_k)
#pragma unroll
  for (int mi = 0; mi < 4; ++mi) {
#pragma unroll
    for (int r = 0; r < 4; ++r) {
      int m = m0 + wm + mi * 16 + quad * 4 + r;
      int b = m >> 10;  // KACT = 1024
      int s = sel_idx[m];
      float gt = gates[m];
      float* orow = out + ((size_t)b * Sz + s) * Dz;
#pragma unroll
      for (int ni = 0; ni < 2; ++ni) {
        int n = n0 + wn + ni * 16 + l16;
        orow[n] = (acc[mi][ni][r] + bias[n]) * gt;
      }
    }
  }
}

extern "C" void kernel_launch(void* const* d_in, const int* in_sizes, int n_in,
                              void* d_out, int out_size, void* d_ws, size_t ws_size,
                              hipStream_t stream) {
  (void)in_sizes; (void)n_in; (void)out_size; (void)ws_size;
  const float* x  = (const float*)d_in[0];
  const float* rw = (const float*)d_in[1];
  const float* rb = (const float*)d_in[2];
  const float* w1 = (const float*)d_in[3];
  const float* b1 = (const float*)d_in[4];
  const float* w2 = (const float*)d_in[5];
  const float* b2 = (const float*)d_in[6];
  float* out = (float*)d_out;

  char* ws = (char*)d_ws;
  float* scores = (float*)ws;  ws += (size_t)Bz * Sz * 4;          // 64 KB
  int*   sel_idx = (int*)ws;   ws += (size_t)Bz * KACT * 4;        // 16 KB
  float* gates = (float*)ws;   ws += (size_t)Bz * KACT * 4;        // 16 KB
  bf16*  w1T = (bf16*)ws;      ws += (size_t)DFFz * Dz * 2;        // 8 MB  [4096][1024]
  bf16*  w2T = (bf16*)ws;      ws += (size_t)Dz * DFFz * 2;        // 8 MB  [1024][4096]
  bf16*  Xsel = (bf16*)ws;     ws += (size_t)Bz * KACT * Dz * 2;   // 8 MB  [4096][1024]
  bf16*  H = (bf16*)ws;        ws += (size_t)Bz * KACT * DFFz * 2; // 32 MB [4096][4096]

  router_k<<<(Bz * Sz) / 4, 256, 0, stream>>>(x, rw, rb, scores, (float4*)out);
  transpose_cvt<<<dim3(DFFz / 32, Dz / 32), dim3(32, 8), 0, stream>>>(w1, w1T, Dz, DFFz);
  transpose_cvt<<<dim3(Dz / 32, DFFz / 32), dim3(32, 8), 0, stream>>>(w2, w2T, DFFz, Dz);
  select_gather_k<<<Bz * (Sz / 16), 256, 0, stream>>>(x, scores, sel_idx, gates, Xsel);
  gemm1_k<<<dim3(DFFz / 128, (Bz * KACT) / 128), 256, 0, stream>>>(Xsel, w1T, b1, H);
  gemm2_k<<<dim3(Dz / 64, (Bz * KACT) / 128), 256, 0, stream>>>(H, w2T, b2, sel_idx, gates, out);
}

// Round 5
// 299.258 us; speedup vs baseline: 1.1982x; 1.0535x over previous
//
#include <hip/hip_runtime.h>
#include <hip/hip_bf16.h>
#include <cstdint>
#include <cstddef>

// Problem constants (B=4, S=4096, D=1024, DFF=4096, K_ACT=1024)
#define Bz 4
#define Sz 4096
#define Dz 1024
#define DFFz 4096
#define KACT 1024

typedef __bf16 bf16;
typedef __attribute__((ext_vector_type(8))) __bf16 bf16x8;
typedef __attribute__((ext_vector_type(4))) __bf16 bf16x4;
typedef __attribute__((ext_vector_type(4))) float f32x4;

__device__ __forceinline__ void async16(const void* g, void* l) {
  __builtin_amdgcn_global_load_lds(
      (const __attribute__((address_space(1))) void*)g,
      (__attribute__((address_space(3))) void*)l, 16, 0, 0);
}

// ---- router + zero: scores[b,s] = x[b,s,:]·rw + rb; also zero out rows ----
__global__ void router_k(const float* __restrict__ x, const float* __restrict__ rw,
                         const float* __restrict__ rb, float* __restrict__ scores,
                         float4* __restrict__ out4) {
  int row = blockIdx.x * 4 + (threadIdx.x >> 6);  // [0, B*S)
  int lane = threadIdx.x & 63;
  const float4* xr = (const float4*)(x + (size_t)row * Dz);
  const float4* wr = (const float4*)rw;
  float acc = 0.f;
#pragma unroll
  for (int i = 0; i < 4; ++i) {
    float4 a = xr[lane + i * 64];
    float4 w = wr[lane + i * 64];
    acc += a.x * w.x + a.y * w.y + a.z * w.z + a.w * w.w;
  }
#pragma unroll
  for (int d = 32; d; d >>= 1) acc += __shfl_down(acc, d, 64);
  if (lane == 0) scores[row] = acc + rb[0];
  float4* o = out4 + (size_t)blockIdx.x * 4 * (Dz / 4);
  const float4 z = make_float4(0.f, 0.f, 0.f, 0.f);
#pragma unroll
  for (int i = 0; i < 4; ++i) o[threadIdx.x + i * 256] = z;
}

// ---------------- transpose + fp32->bf16 convert: out[C][R] = in[R][C] ----------------
__global__ void transpose_cvt(const float* __restrict__ in, bf16* __restrict__ out,
                              int R, int C) {
  __shared__ float t[32][33];
  int c0 = blockIdx.x * 32, r0 = blockIdx.y * 32;
  int tx = threadIdx.x, ty = threadIdx.y;  // (32, 8)
#pragma unroll
  for (int i = 0; i < 32; i += 8) t[ty + i][tx] = in[(size_t)(r0 + ty + i) * C + c0 + tx];
  __syncthreads();
#pragma unroll
  for (int i = 0; i < 32; i += 8)
    out[(size_t)(c0 + ty + i) * R + r0 + tx] = (bf16)t[tx][ty + i];
}

// ---- select top-K per batch, 16 tokens/block: scores staged in LDS once ----
__global__ __launch_bounds__(256) void select_gather_k(
    const float* __restrict__ x, const float* __restrict__ scores,
    int* __restrict__ sel_idx, float* __restrict__ gates, bf16* __restrict__ Xsel) {
  int b = blockIdx.x >> 8;            // 256 blocks per batch row
  int s0 = (blockIdx.x & 255) * 16;   // first of 16 tokens
  __shared__ float sc[Sz];
  __shared__ int red[16][4];
  __shared__ int rk[16];
  const int tid = threadIdx.x;
  const int wave = tid >> 6, lane = tid & 63;
  const float* srow = scores + (size_t)b * Sz;
#pragma unroll
  for (int i = 0; i < 4; ++i)
    ((float4*)sc)[tid + i * 256] = ((const float4*)srow)[tid + i * 256];
  __syncthreads();
  float mine[16];
#pragma unroll
  for (int j = 0; j < 16; ++j) mine[j] = sc[s0 + j];
  int cnt[16] = {};
  for (int t = tid; t < Sz; t += 256) {
    float o = sc[t];
#pragma unroll
    for (int j = 0; j < 16; ++j)
      cnt[j] += (o > mine[j]) || (o == mine[j] && t < s0 + j);
  }
#pragma unroll
  for (int j = 0; j < 16; ++j) {
    int c = cnt[j];
#pragma unroll
    for (int d = 32; d; d >>= 1) c += __shfl_down(c, d, 64);
    if (lane == 0) red[j][wave] = c;
  }
  __syncthreads();
  if (tid < 16) {
    int rank = red[tid][0] + red[tid][1] + red[tid][2] + red[tid][3];
    rk[tid] = rank;
    if (rank < KACT) {
      int m = b * KACT + rank;
      sel_idx[m] = s0 + tid;
      gates[m] = 1.f / (1.f + expf(-sc[s0 + tid]));
    }
  }
  __syncthreads();
#pragma unroll
  for (int j = 0; j < 16; ++j) {
    int rank = rk[j];
    if (rank >= KACT) continue;
    int m = b * KACT + rank;
    float4 v = ((const float4*)(x + ((size_t)b * Sz + s0 + j) * Dz))[tid];
    bf16x4 o = {(bf16)v.x, (bf16)v.y, (bf16)v.z, (bf16)v.w};
    ((bf16x4*)(Xsel + (size_t)m * Dz))[tid] = o;
  }
}

// ======== BK=64 MFMA K-loop: LDS = two consecutive [128][32] half-blocks ========
// staging: thread tid stages row=tid>>2, kc=(tid&3)*8 within each half -> lds elem tid*8
// (wave-uniform base + lane*16B, required by global_load_lds). ds_read pattern identical
// to the proven BK=32 layout (stride 32 elems) -> same bank behavior, half the barriers.
#define GEMM_BK64_STEP(k0)                                                     \
  _Pragma("unroll")                                                            \
  for (int h = 0; h < 2; ++h) {                                                \
    async16(Ag + (k0) + h * 32, &As[h * 4096 + tid * 8]);                      \
    async16(Ag + (size_t)64 * K + (k0) + h * 32, &As[h * 4096 + 2048 + tid * 8]); \
    async16(Bg + (k0) + h * 32, &Bs[h * 4096 + tid * 8]);                      \
    async16(Bg + (size_t)64 * K + (k0) + h * 32, &Bs[h * 4096 + 2048 + tid * 8]); \
  }                                                                            \
  __syncthreads();                                                             \
  _Pragma("unroll")                                                            \
  for (int h = 0; h < 2; ++h) {                                                \
    bf16x8 af[4], bfr[4];                                                      \
    _Pragma("unroll")                                                          \
    for (int i = 0; i < 4; ++i) {                                              \
      af[i] = *(const bf16x8*)&As[h * 4096 + (wm + i * 16 + l16) * 32 + quad * 8]; \
      bfr[i] = *(const bf16x8*)&Bs[h * 4096 + (wn + i * 16 + l16) * 32 + quad * 8]; \
    }                                                                          \
    _Pragma("unroll")                                                          \
    for (int mi = 0; mi < 4; ++mi)                                             \
      _Pragma("unroll")                                                        \
      for (int ni = 0; ni < 4; ++ni)                                           \
        acc[mi][ni] = __builtin_amdgcn_mfma_f32_16x16x32_bf16(af[mi], bfr[ni], acc[mi][ni], 0, 0, 0); \
  }                                                                            \
  __syncthreads();

// ---------------- GEMM1: H = gelu(Xsel @ w1 + b1), M=4096 N=4096 K=1024 ----------------
__global__ __launch_bounds__(256) void gemm1_k(const bf16* __restrict__ A,
                                               const bf16* __restrict__ Bt,
                                               const float* __restrict__ bias,
                                               bf16* __restrict__ H) {
  constexpr int K = Dz, N = DFFz;
  __shared__ __align__(16) bf16 As[2 * 128 * 32];  // 16 KB
  __shared__ __align__(16) bf16 Bs[2 * 128 * 32];  // 16 KB
  const int tid = threadIdx.x;
  const int wave = tid >> 6, lane = tid & 63;
  const int quad = lane >> 4, l16 = lane & 15;
  const int m0 = blockIdx.y * 128, n0 = blockIdx.x * 128;
  const int wm = (wave >> 1) * 64, wn = (wave & 1) * 64;
  const int r0 = tid >> 2;
  const int kk = (tid & 3) * 8;
  f32x4 acc[4][4] = {};
  const bf16* Ag = A + (size_t)(m0 + r0) * K + kk;
  const bf16* Bg = Bt + (size_t)(n0 + r0) * K + kk;

  for (int k0 = 0; k0 < K; k0 += 64) {
    GEMM_BK64_STEP(k0)
  }

  // epilogue: bias + exact GELU -> bf16   (C/D layout: col=lane&15, row=quad*4+reg)
#pragma unroll
  for (int mi = 0; mi < 4; ++mi) {
    int mbase = m0 + wm + mi * 16 + quad * 4;
#pragma unroll
    for (int ni = 0; ni < 4; ++ni) {
      int n = n0 + wn + ni * 16 + l16;
      float bn = bias[n];
#pragma unroll
      for (int r = 0; r < 4; ++r) {
        float z = acc[mi][ni][r] + bn;
        float g = 0.5f * z * (1.f + erff(z * 0.70710678118654752f));
        H[(size_t)(mbase + r) * N + n] = (bf16)g;
      }
    }
  }
}

// ---- GEMM2 main, split-K=2 non-atomic: P[c] = (H @ w2)_chunk as bf16 partials ----
// M=4096 N=1024 K=4096 -> 2 chunks of 2048; grid 8x32x2 = 512 blocks (2/CU).
__global__ __launch_bounds__(256) void gemm2_k(const bf16* __restrict__ A,
                                               const bf16* __restrict__ Bt,
                                               bf16* __restrict__ P) {
  constexpr int K = DFFz;
  __shared__ __align__(16) bf16 As[2 * 128 * 32];
  __shared__ __align__(16) bf16 Bs[2 * 128 * 32];
  const int tid = threadIdx.x;
  const int wave = tid >> 6, lane = tid & 63;
  const int quad = lane >> 4, l16 = lane & 15;
  const int m0 = blockIdx.y * 128, n0 = blockIdx.x * 128;
  const int kc0 = blockIdx.z * 2048;
  const int wm = (wave >> 1) * 64, wn = (wave & 1) * 64;
  const int r0 = tid >> 2;
  const int kk = (tid & 3) * 8;
  f32x4 acc[4][4] = {};
  const bf16* Ag = A + (size_t)(m0 + r0) * K + kc0 + kk;
  const bf16* Bg = Bt + (size_t)(n0 + r0) * K + kc0 + kk;

  for (int k0 = 0; k0 < 2048; k0 += 64) {
    GEMM_BK64_STEP(k0)
  }

  // store bf16 partial (no bias/gate yet)
  bf16* Pc = P + (size_t)blockIdx.z * Bz * KACT * Dz;
#pragma unroll
  for (int mi = 0; mi < 4; ++mi) {
    int mbase = m0 + wm + mi * 16 + quad * 4;
#pragma unroll
    for (int ni = 0; ni < 4; ++ni) {
      int n = n0 + wn + ni * 16 + l16;
#pragma unroll
      for (int r = 0; r < 4; ++r)
        Pc[(size_t)(mbase + r) * Dz + n] = (bf16)acc[mi][ni][r];
    }
  }
}

// ---- reduce partials + bias + gate + scatter: out[b,sel[m],:] = (P0+P1+b2)*gate ----
__global__ __launch_bounds__(256) void reduce_k(const bf16* __restrict__ P,
                                                const float* __restrict__ bias,
                                                const int* __restrict__ sel_idx,
                                                const float* __restrict__ gates,
                                                float* __restrict__ out) {
  int m = blockIdx.x;
  int b = m >> 10;
  int s = sel_idx[m];
  float gt = gates[m];
  int tid = threadIdx.x;
  const bf16x4* p0 = (const bf16x4*)(P + (size_t)m * Dz);
  const bf16x4* p1 = (const bf16x4*)(P + (size_t)Bz * KACT * Dz + (size_t)m * Dz);
  const float4* bv = (const float4*)bias;
  float4* orow = (float4*)(out + ((size_t)b * Sz + s) * Dz);
  bf16x4 a = p0[tid], c = p1[tid];
  float4 bb = bv[tid];
  float4 o;
  o.x = ((float)a[0] + (float)c[0] + bb.x) * gt;
  o.y = ((float)a[1] + (float)c[1] + bb.y) * gt;
  o.z = ((float)a[2] + (float)c[2] + bb.z) * gt;
  o.w = ((float)a[3] + (float)c[3] + bb.w) * gt;
  orow[tid] = o;
}

extern "C" void kernel_launch(void* const* d_in, const int* in_sizes, int n_in,
                              void* d_out, int out_size, void* d_ws, size_t ws_size,
                              hipStream_t stream) {
  (void)in_sizes; (void)n_in; (void)out_size; (void)ws_size;
  const float* x  = (const float*)d_in[0];
  const float* rw = (const float*)d_in[1];
  const float* rb = (const float*)d_in[2];
  const float* w1 = (const float*)d_in[3];
  const float* b1 = (const float*)d_in[4];
  const float* w2 = (const float*)d_in[5];
  const float* b2 = (const float*)d_in[6];
  float* out = (float*)d_out;

  char* ws = (char*)d_ws;
  float* scores = (float*)ws;  ws += (size_t)Bz * Sz * 4;          // 64 KB
  int*   sel_idx = (int*)ws;   ws += (size_t)Bz * KACT * 4;        // 16 KB
  float* gates = (float*)ws;   ws += (size_t)Bz * KACT * 4;        // 16 KB
  bf16*  w2T = (bf16*)ws;      ws += (size_t)Dz * DFFz * 2;        // 8 MB  [1024][4096]
  bf16*  H = (bf16*)ws;        ws += (size_t)Bz * KACT * DFFz * 2; // 32 MB [4096][4096]
  bf16*  w1T = (bf16*)ws;      ws += (size_t)DFFz * Dz * 2;        // 8 MB  [4096][1024]
  bf16*  Xsel = (bf16*)ws;     ws += (size_t)Bz * KACT * Dz * 2;   // 8 MB  [4096][1024]
  // P (2 x 8 MB bf16 partials) overlays w1T+Xsel, both dead after gemm1.
  bf16*  P = w1T;

  router_k<<<(Bz * Sz) / 4, 256, 0, stream>>>(x, rw, rb, scores, (float4*)out);
  transpose_cvt<<<dim3(DFFz / 32, Dz / 32), dim3(32, 8), 0, stream>>>(w1, w1T, Dz, DFFz);
  transpose_cvt<<<dim3(Dz / 32, DFFz / 32), dim3(32, 8), 0, stream>>>(w2, w2T, DFFz, Dz);
  select_gather_k<<<Bz * (Sz / 16), 256, 0, stream>>>(x, scores, sel_idx, gates, Xsel);
  gemm1_k<<<dim3(DFFz / 128, (Bz * KACT) / 128), 256, 0, stream>>>(Xsel, w1T, b1, H);
  gemm2_k<<<dim3(Dz / 128, (Bz * KACT) / 128, 2), 256, 0, stream>>>(H, w2T, P);
  reduce_k<<<Bz * KACT, 256, 0, stream>>>(P, b2, sel_idx, gates, out);
}

// Round 6
// 292.966 us; speedup vs baseline: 1.2239x; 1.0215x over previous
//
#include <hip/hip_runtime.h>
#include <hip/hip_bf16.h>
#include <cstdint>
#include <cstddef>

// Problem constants (B=4, S=4096, D=1024, DFF=4096, K_ACT=1024)
#define Bz 4
#define Sz 4096
#define Dz 1024
#define DFFz 4096
#define KACT 1024

typedef __bf16 bf16;
typedef __attribute__((ext_vector_type(8))) __bf16 bf16x8;
typedef __attribute__((ext_vector_type(4))) __bf16 bf16x4;
typedef __attribute__((ext_vector_type(4))) float f32x4;

__device__ __forceinline__ void async16(const void* g, void* l) {
  __builtin_amdgcn_global_load_lds(
      (const __attribute__((address_space(1))) void*)g,
      (__attribute__((address_space(3))) void*)l, 16, 0, 0);
}

// ---- router + zero: scores[b,s] = x[b,s,:]·rw + rb; also zero out rows ----
__global__ void router_k(const float* __restrict__ x, const float* __restrict__ rw,
                         const float* __restrict__ rb, float* __restrict__ scores,
                         float4* __restrict__ out4) {
  int row = blockIdx.x * 4 + (threadIdx.x >> 6);  // [0, B*S)
  int lane = threadIdx.x & 63;
  const float4* xr = (const float4*)(x + (size_t)row * Dz);
  const float4* wr = (const float4*)rw;
  float acc = 0.f;
#pragma unroll
  for (int i = 0; i < 4; ++i) {
    float4 a = xr[lane + i * 64];
    float4 w = wr[lane + i * 64];
    acc += a.x * w.x + a.y * w.y + a.z * w.z + a.w * w.w;
  }
#pragma unroll
  for (int d = 32; d; d >>= 1) acc += __shfl_down(acc, d, 64);
  if (lane == 0) scores[row] = acc + rb[0];
  float4* o = out4 + (size_t)blockIdx.x * 4 * (Dz / 4);
  const float4 z = make_float4(0.f, 0.f, 0.f, 0.f);
#pragma unroll
  for (int i = 0; i < 4; ++i) o[threadIdx.x + i * 256] = z;
}

// ---------------- transpose + fp32->bf16 convert: out[C][R] = in[R][C] ----------------
__global__ void transpose_cvt(const float* __restrict__ in, bf16* __restrict__ out,
                              int R, int C) {
  __shared__ float t[32][33];
  int c0 = blockIdx.x * 32, r0 = blockIdx.y * 32;
  int tx = threadIdx.x, ty = threadIdx.y;  // (32, 8)
#pragma unroll
  for (int i = 0; i < 32; i += 8) t[ty + i][tx] = in[(size_t)(r0 + ty + i) * C + c0 + tx];
  __syncthreads();
#pragma unroll
  for (int i = 0; i < 32; i += 8)
    out[(size_t)(c0 + ty + i) * R + r0 + tx] = (bf16)t[tx][ty + i];
}

// ---- select top-K per batch, 16 tokens/block: scores staged in LDS once ----
__global__ __launch_bounds__(256) void select_gather_k(
    const float* __restrict__ x, const float* __restrict__ scores,
    int* __restrict__ sel_idx, float* __restrict__ gates, bf16* __restrict__ Xsel) {
  int b = blockIdx.x >> 8;            // 256 blocks per batch row
  int s0 = (blockIdx.x & 255) * 16;   // first of 16 tokens
  __shared__ float sc[Sz];
  __shared__ int red[16][4];
  __shared__ int rk[16];
  const int tid = threadIdx.x;
  const int wave = tid >> 6, lane = tid & 63;
  const float* srow = scores + (size_t)b * Sz;
#pragma unroll
  for (int i = 0; i < 4; ++i)
    ((float4*)sc)[tid + i * 256] = ((const float4*)srow)[tid + i * 256];
  __syncthreads();
  float mine[16];
#pragma unroll
  for (int j = 0; j < 16; ++j) mine[j] = sc[s0 + j];
  int cnt[16] = {};
  for (int t = tid; t < Sz; t += 256) {
    float o = sc[t];
#pragma unroll
    for (int j = 0; j < 16; ++j)
      cnt[j] += (o > mine[j]) || (o == mine[j] && t < s0 + j);
  }
#pragma unroll
  for (int j = 0; j < 16; ++j) {
    int c = cnt[j];
#pragma unroll
    for (int d = 32; d; d >>= 1) c += __shfl_down(c, d, 64);
    if (lane == 0) red[j][wave] = c;
  }
  __syncthreads();
  if (tid < 16) {
    int rank = red[tid][0] + red[tid][1] + red[tid][2] + red[tid][3];
    rk[tid] = rank;
    if (rank < KACT) {
      int m = b * KACT + rank;
      sel_idx[m] = s0 + tid;
      gates[m] = 1.f / (1.f + expf(-sc[s0 + tid]));
    }
  }
  __syncthreads();
#pragma unroll
  for (int j = 0; j < 16; ++j) {
    int rank = rk[j];
    if (rank >= KACT) continue;
    int m = b * KACT + rank;
    float4 v = ((const float4*)(x + ((size_t)b * Sz + s0 + j) * Dz))[tid];
    bf16x4 o = {(bf16)v.x, (bf16)v.y, (bf16)v.z, (bf16)v.w};
    ((bf16x4*)(Xsel + (size_t)m * Dz))[tid] = o;
  }
}

// ======== producer/consumer pipelined GEMM: 512 threads, waves 0-3 compute,
// waves 4-7 stage via global_load_lds into double-buffered BK=64 LDS.
// Consumers carry no vmcnt -> their barrier is cheap; producers' vmcnt(0) drain
// for tile it+1 overlaps consumers' MFMA on tile it. Barrier counts match.
#define PROD_ISSUE(buf, k0)                                                    \
  _Pragma("unroll")                                                            \
  for (int h = 0; h < 2; ++h) {                                                \
    async16(Ag + (k0) + h * 32, &As[buf][h * 4096 + q * 8]);                   \
    async16(Ag + (size_t)64 * K + (k0) + h * 32, &As[buf][h * 4096 + 2048 + q * 8]); \
    async16(Bg + (k0) + h * 32, &Bs[buf][h * 4096 + q * 8]);                   \
    async16(Bg + (size_t)64 * K + (k0) + h * 32, &Bs[buf][h * 4096 + 2048 + q * 8]); \
  }

#define PIPE_GEMM_BODY(KV, KOFF, NITER)                                        \
  __shared__ __align__(16) bf16 As[2][2 * 128 * 32];  /* 2 x 16 KB */          \
  __shared__ __align__(16) bf16 Bs[2][2 * 128 * 32];                           \
  constexpr int K = (KV);                                                      \
  const int tid = threadIdx.x;                                                 \
  const int wave = tid >> 6, lane = tid & 63;                                  \
  const int quad = lane >> 4, l16 = lane & 15;                                 \
  const int m0 = blockIdx.y * 128, n0 = blockIdx.x * 128;                      \
  const int wm = (wave >> 1) * 64, wn = (wave & 1) * 64;                       \
  const int q = tid & 255;                                                     \
  const bf16* Ag = A + (size_t)(m0 + (q >> 2)) * K + (KOFF) + (q & 3) * 8;     \
  const bf16* Bg = Bt + (size_t)(n0 + (q >> 2)) * K + (KOFF) + (q & 3) * 8;    \
  f32x4 acc[4][4] = {};                                                        \
  if (wave >= 4) { PROD_ISSUE(0, 0) }                                          \
  __syncthreads();                                                             \
  for (int it = 0; it < (NITER); ++it) {                                       \
    if (wave >= 4) {                                                           \
      if (it + 1 < (NITER)) { PROD_ISSUE((it + 1) & 1, (it + 1) * 64) }        \
    } else {                                                                   \
      const int cur = it & 1;                                                  \
      _Pragma("unroll")                                                        \
      for (int h = 0; h < 2; ++h) {                                            \
        bf16x8 af[4], bfr[4];                                                  \
        _Pragma("unroll")                                                      \
        for (int i = 0; i < 4; ++i) {                                          \
          af[i] = *(const bf16x8*)&As[cur][h * 4096 + (wm + i * 16 + l16) * 32 + quad * 8]; \
          bfr[i] = *(const bf16x8*)&Bs[cur][h * 4096 + (wn + i * 16 + l16) * 32 + quad * 8]; \
        }                                                                      \
        _Pragma("unroll")                                                      \
        for (int mi = 0; mi < 4; ++mi)                                         \
          _Pragma("unroll")                                                    \
          for (int ni = 0; ni < 4; ++ni)                                       \
            acc[mi][ni] = __builtin_amdgcn_mfma_f32_16x16x32_bf16(af[mi], bfr[ni], acc[mi][ni], 0, 0, 0); \
      }                                                                        \
    }                                                                          \
    __syncthreads();                                                           \
  }

// ---------------- GEMM1: H = gelu(Xsel @ w1 + b1), M=4096 N=4096 K=1024 ----------------
__global__ __launch_bounds__(512, 4) void gemm1_k(const bf16* __restrict__ A,
                                                  const bf16* __restrict__ Bt,
                                                  const float* __restrict__ bias,
                                                  bf16* __restrict__ H) {
  constexpr int N = DFFz;
  PIPE_GEMM_BODY(Dz, 0, Dz / 64)
  if (wave < 4) {
    // epilogue: bias + exact GELU -> bf16   (C/D layout: col=lane&15, row=quad*4+reg)
#pragma unroll
    for (int mi = 0; mi < 4; ++mi) {
      int mbase = m0 + wm + mi * 16 + quad * 4;
#pragma unroll
      for (int ni = 0; ni < 4; ++ni) {
        int n = n0 + wn + ni * 16 + l16;
        float bn = bias[n];
#pragma unroll
        for (int r = 0; r < 4; ++r) {
          float z = acc[mi][ni][r] + bn;
          float g = 0.5f * z * (1.f + erff(z * 0.70710678118654752f));
          H[(size_t)(mbase + r) * N + n] = (bf16)g;
        }
      }
    }
  }
}

// ---- GEMM2 main, split-K=2 non-atomic: P[c] = (H @ w2)_chunk as bf16 partials ----
// M=4096 N=1024 K=4096 -> 2 chunks of 2048; grid 8x32x2 = 512 blocks.
__global__ __launch_bounds__(512, 4) void gemm2_k(const bf16* __restrict__ A,
                                                  const bf16* __restrict__ Bt,
                                                  bf16* __restrict__ P) {
  PIPE_GEMM_BODY(DFFz, blockIdx.z * 2048, 2048 / 64)
  if (wave < 4) {
    bf16* Pc = P + (size_t)blockIdx.z * Bz * KACT * Dz;
#pragma unroll
    for (int mi = 0; mi < 4; ++mi) {
      int mbase = m0 + wm + mi * 16 + quad * 4;
#pragma unroll
      for (int ni = 0; ni < 4; ++ni) {
        int n = n0 + wn + ni * 16 + l16;
#pragma unroll
        for (int r = 0; r < 4; ++r)
          Pc[(size_t)(mbase + r) * Dz + n] = (bf16)acc[mi][ni][r];
      }
    }
  }
}

// ---- reduce partials + bias + gate + scatter: out[b,sel[m],:] = (P0+P1+b2)*gate ----
__global__ __launch_bounds__(256) void reduce_k(const bf16* __restrict__ P,
                                                const float* __restrict__ bias,
                                                const int* __restrict__ sel_idx,
                                                const float* __restrict__ gates,
                                                float* __restrict__ out) {
  int m = blockIdx.x;
  int b = m >> 10;
  int s = sel_idx[m];
  float gt = gates[m];
  int tid = threadIdx.x;
  const bf16x4* p0 = (const bf16x4*)(P + (size_t)m * Dz);
  const bf16x4* p1 = (const bf16x4*)(P + (size_t)Bz * KACT * Dz + (size_t)m * Dz);
  const float4* bv = (const float4*)bias;
  float4* orow = (float4*)(out + ((size_t)b * Sz + s) * Dz);
  bf16x4 a = p0[tid], c = p1[tid];
  float4 bb = bv[tid];
  float4 o;
  o.x = ((float)a[0] + (float)c[0] + bb.x) * gt;
  o.y = ((float)a[1] + (float)c[1] + bb.y) * gt;
  o.z = ((float)a[2] + (float)c[2] + bb.z) * gt;
  o.w = ((float)a[3] + (float)c[3] + bb.w) * gt;
  orow[tid] = o;
}

extern "C" void kernel_launch(void* const* d_in, const int* in_sizes, int n_in,
                              void* d_out, int out_size, void* d_ws, size_t ws_size,
                              hipStream_t stream) {
  (void)in_sizes; (void)n_in; (void)out_size; (void)ws_size;
  const float* x  = (const float*)d_in[0];
  const float* rw = (const float*)d_in[1];
  const float* rb = (const float*)d_in[2];
  const float* w1 = (const float*)d_in[3];
  const float* b1 = (const float*)d_in[4];
  const float* w2 = (const float*)d_in[5];
  const float* b2 = (const float*)d_in[6];
  float* out = (float*)d_out;

  char* ws = (char*)d_ws;
  float* scores = (float*)ws;  ws += (size_t)Bz * Sz * 4;          // 64 KB
  int*   sel_idx = (int*)ws;   ws += (size_t)Bz * KACT * 4;        // 16 KB
  float* gates = (float*)ws;   ws += (size_t)Bz * KACT * 4;        // 16 KB
  bf16*  w2T = (bf16*)ws;      ws += (size_t)Dz * DFFz * 2;        // 8 MB  [1024][4096]
  bf16*  H = (bf16*)ws;        ws += (size_t)Bz * KACT * DFFz * 2; // 32 MB [4096][4096]
  bf16*  w1T = (bf16*)ws;      ws += (size_t)DFFz * Dz * 2;        // 8 MB  [4096][1024]
  bf16*  Xsel = (bf16*)ws;     ws += (size_t)Bz * KACT * Dz * 2;   // 8 MB  [4096][1024]
  // P (2 x 8 MB bf16 partials) overlays w1T+Xsel, both dead after gemm1.
  bf16*  P = w1T;

  router_k<<<(Bz * Sz) / 4, 256, 0, stream>>>(x, rw, rb, scores, (float4*)out);
  transpose_cvt<<<dim3(DFFz / 32, Dz / 32), dim3(32, 8), 0, stream>>>(w1, w1T, Dz, DFFz);
  transpose_cvt<<<dim3(Dz / 32, DFFz / 32), dim3(32, 8), 0, stream>>>(w2, w2T, DFFz, Dz);
  select_gather_k<<<Bz * (Sz / 16), 256, 0, stream>>>(x, scores, sel_idx, gates, Xsel);
  gemm1_k<<<dim3(DFFz / 128, (Bz * KACT) / 128), 512, 0, stream>>>(Xsel, w1T, b1, H);
  gemm2_k<<<dim3(Dz / 128, (Bz * KACT) / 128, 2), 512, 0, stream>>>(H, w2T, P);
  reduce_k<<<Bz * KACT, 256, 0, stream>>>(P, b2, sel_idx, gates, out);
}

// Round 8
// 291.916 us; speedup vs baseline: 1.2283x; 1.0036x over previous
//
#include <hip/hip_runtime.h>
#include <hip/hip_bf16.h>
#include <cstdint>
#include <cstddef>

// Problem constants (B=4, S=4096, D=1024, DFF=4096, K_ACT=1024)
#define Bz 4
#define Sz 4096
#define Dz 1024
#define DFFz 4096
#define KACT 1024

typedef __bf16 bf16;
typedef __attribute__((ext_vector_type(8))) __bf16 bf16x8;
typedef __attribute__((ext_vector_type(4))) __bf16 bf16x4;
typedef __attribute__((ext_vector_type(4))) float f32x4;

__device__ __forceinline__ void async16(const void* g, void* l) {
  __builtin_amdgcn_global_load_lds(
      (const __attribute__((address_space(1))) void*)g,
      (__attribute__((address_space(3))) void*)l, 16, 0, 0);
}

// ---- fused prep: [0,4096) router+zero | [4096,8192) w1 transpose | [8192,12288) w2 transpose ----
__global__ __launch_bounds__(256) void prep_k(const float* __restrict__ x,
                                              const float* __restrict__ rw,
                                              const float* __restrict__ rb,
                                              float* __restrict__ scores,
                                              float4* __restrict__ out4,
                                              const float* __restrict__ w1,
                                              bf16* __restrict__ w1T,
                                              const float* __restrict__ w2,
                                              bf16* __restrict__ w2T) {
  __shared__ float t[32][33];
  const int bid = blockIdx.x;
  const int tid = threadIdx.x;
  if (bid < 4096) {
    int row = bid * 4 + (tid >> 6);
    int lane = tid & 63;
    const float4* xr = (const float4*)(x + (size_t)row * Dz);
    const float4* wr = (const float4*)rw;
    float acc = 0.f;
#pragma unroll
    for (int i = 0; i < 4; ++i) {
      float4 a = xr[lane + i * 64];
      float4 w = wr[lane + i * 64];
      acc += a.x * w.x + a.y * w.y + a.z * w.z + a.w * w.w;
    }
#pragma unroll
    for (int d = 32; d; d >>= 1) acc += __shfl_down(acc, d, 64);
    if (lane == 0) scores[row] = acc + rb[0];
    float4* o = out4 + (size_t)bid * 4 * (Dz / 4);
    const float4 z = make_float4(0.f, 0.f, 0.f, 0.f);
#pragma unroll
    for (int i = 0; i < 4; ++i) o[tid + i * 256] = z;
  } else {
    const float* in; bf16* outp; int R, C, bx, by;
    if (bid < 8192) {
      in = w1; outp = w1T; R = Dz; C = DFFz;
      bx = (bid - 4096) & 127; by = (bid - 4096) >> 7;   // (128, 32)
    } else {
      in = w2; outp = w2T; R = DFFz; C = Dz;
      bx = (bid - 8192) & 31; by = (bid - 8192) >> 5;    // (32, 128)
    }
    int c0 = bx * 32, r0 = by * 32;
    int tx = tid & 31, ty = tid >> 5;  // (32, 8)
#pragma unroll
    for (int i = 0; i < 32; i += 8) t[ty + i][tx] = in[(size_t)(r0 + ty + i) * C + c0 + tx];
    __syncthreads();
#pragma unroll
    for (int i = 0; i < 32; i += 8)
      outp[(size_t)(c0 + ty + i) * R + r0 + tx] = (bf16)t[tx][ty + i];
  }
}

// ---- select top-K per batch, 16 tokens/block: scores staged in LDS once ----
__global__ __launch_bounds__(256) void select_gather_k(
    const float* __restrict__ x, const float* __restrict__ scores,
    int* __restrict__ sel_idx, float* __restrict__ gates, bf16* __restrict__ Xsel) {
  int b = blockIdx.x >> 8;            // 256 blocks per batch row
  int s0 = (blockIdx.x & 255) * 16;   // first of 16 tokens
  __shared__ float sc[Sz];
  __shared__ int red[16][4];
  __shared__ int rk[16];
  const int tid = threadIdx.x;
  const int wave = tid >> 6, lane = tid & 63;
  const float* srow = scores + (size_t)b * Sz;
#pragma unroll
  for (int i = 0; i < 4; ++i)
    ((float4*)sc)[tid + i * 256] = ((const float4*)srow)[tid + i * 256];
  __syncthreads();
  float mine[16];
#pragma unroll
  for (int j = 0; j < 16; ++j) mine[j] = sc[s0 + j];
  int cnt[16] = {};
  for (int t = tid; t < Sz; t += 256) {
    float o = sc[t];
#pragma unroll
    for (int j = 0; j < 16; ++j)
      cnt[j] += (o > mine[j]) || (o == mine[j] && t < s0 + j);
  }
#pragma unroll
  for (int j = 0; j < 16; ++j) {
    int c = cnt[j];
#pragma unroll
    for (int d = 32; d; d >>= 1) c += __shfl_down(c, d, 64);
    if (lane == 0) red[j][wave] = c;
  }
  __syncthreads();
  if (tid < 16) {
    int rank = red[tid][0] + red[tid][1] + red[tid][2] + red[tid][3];
    rk[tid] = rank;
    if (rank < KACT) {
      int m = b * KACT + rank;
      sel_idx[m] = s0 + tid;
      gates[m] = 1.f / (1.f + expf(-sc[s0 + tid]));
    }
  }
  __syncthreads();
#pragma unroll
  for (int j = 0; j < 16; ++j) {
    int rank = rk[j];
    if (rank >= KACT) continue;
    int m = b * KACT + rank;
    float4 v = ((const float4*)(x + ((size_t)b * Sz + s0 + j) * Dz))[tid];
    bf16x4 o = {(bf16)v.x, (bf16)v.y, (bf16)v.z, (bf16)v.w};
    ((bf16x4*)(Xsel + (size_t)m * Dz))[tid] = o;
  }
}

// ======== producer/consumer pipelined GEMM, BK=32 double-buffer (32 KB LDS).
// 512 threads: waves 0-3 compute, waves 4-7 stage via global_load_lds.
// __launch_bounds__(512,4): NO forced 64-VGPR cap (R7's (512,8) caused spill +
// graph-replay corruption). If natural VGPR <= 64 (R6 hit exactly 64), HW gives
// 8 waves/EU -> 4 blocks/CU; worst case 2 blocks/CU == R6 perf.
#define PROD_ISSUE(buf, k0)                                                    \
  async16(Ag + (k0), &As[buf][q * 8]);                                         \
  async16(Ag + (size_t)64 * K + (k0), &As[buf][2048 + q * 8]);                 \
  async16(Bg + (k0), &Bs[buf][q * 8]);                                         \
  async16(Bg + (size_t)64 * K + (k0), &Bs[buf][2048 + q * 8]);

#define PIPE_GEMM_BODY(KV, KOFF, NITER)                                        \
  __shared__ __align__(16) bf16 As[2][128 * 32];  /* 2 x 8 KB */               \
  __shared__ __align__(16) bf16 Bs[2][128 * 32];                               \
  constexpr int K = (KV);                                                      \
  const int tid = threadIdx.x;                                                 \
  const int wave = tid >> 6, lane = tid & 63;                                  \
  const int quad = lane >> 4, l16 = lane & 15;                                 \
  const int m0 = blockIdx.y * 128, n0 = blockIdx.x * 128;                      \
  const int wm = (wave >> 1) * 64, wn = (wave & 1) * 64;                       \
  const int q = tid & 255;                                                     \
  const bf16* Ag = A + (size_t)(m0 + (q >> 2)) * K + (KOFF) + (q & 3) * 8;     \
  const bf16* Bg = Bt + (size_t)(n0 + (q >> 2)) * K + (KOFF) + (q & 3) * 8;    \
  f32x4 acc[4][4] = {};                                                        \
  if (wave >= 4) { PROD_ISSUE(0, 0) }                                          \
  __syncthreads();                                                             \
  for (int it = 0; it < (NITER); ++it) {                                       \
    if (wave >= 4) {                                                           \
      if (it + 1 < (NITER)) { PROD_ISSUE((it + 1) & 1, (it + 1) * 32) }        \
    } else {                                                                   \
      const int cur = it & 1;                                                  \
      bf16x8 af[4], bfr[4];                                                    \
      _Pragma("unroll")                                                        \
      for (int i = 0; i < 4; ++i) {                                            \
        af[i] = *(const bf16x8*)&As[cur][(wm + i * 16 + l16) * 32 + quad * 8]; \
        bfr[i] = *(const bf16x8*)&Bs[cur][(wn + i * 16 + l16) * 32 + quad * 8]; \
      }                                                                        \
      _Pragma("unroll")                                                        \
      for (int mi = 0; mi < 4; ++mi)                                           \
        _Pragma("unroll")                                                      \
        for (int ni = 0; ni < 4; ++ni)                                         \
          acc[mi][ni] = __builtin_amdgcn_mfma_f32_16x16x32_bf16(af[mi], bfr[ni], acc[mi][ni], 0, 0, 0); \
    }                                                                          \
    __syncthreads();                                                           \
  }

// ---------------- GEMM1: H = gelu(Xsel @ w1 + b1), M=4096 N=4096 K=1024 ----------------
__global__ __launch_bounds__(512, 4) void gemm1_k(const bf16* __restrict__ A,
                                                  const bf16* __restrict__ Bt,
                                                  const float* __restrict__ bias,
                                                  bf16* __restrict__ H) {
  constexpr int N = DFFz;
  PIPE_GEMM_BODY(Dz, 0, Dz / 32)
  if (wave < 4) {
    // epilogue: bias + exact GELU -> bf16   (C/D layout: col=lane&15, row=quad*4+reg)
#pragma unroll
    for (int mi = 0; mi < 4; ++mi) {
      int mbase = m0 + wm + mi * 16 + quad * 4;
#pragma unroll
      for (int ni = 0; ni < 4; ++ni) {
        int n = n0 + wn + ni * 16 + l16;
        float bn = bias[n];
#pragma unroll
        for (int r = 0; r < 4; ++r) {
          float z = acc[mi][ni][r] + bn;
          float g = 0.5f * z * (1.f + erff(z * 0.70710678118654752f));
          H[(size_t)(mbase + r) * N + n] = (bf16)g;
        }
      }
    }
  }
}

// ---- GEMM2 main, split-K=2 non-atomic: P[c] = (H @ w2)_chunk as bf16 partials ----
// M=4096 N=1024 K=4096 -> 2 chunks of 2048; grid 8x32x2 = 512 blocks.
__global__ __launch_bounds__(512, 4) void gemm2_k(const bf16* __restrict__ A,
                                                  const bf16* __restrict__ Bt,
                                                  bf16* __restrict__ P) {
  PIPE_GEMM_BODY(DFFz, blockIdx.z * 2048, 2048 / 32)
  if (wave < 4) {
    bf16* Pc = P + (size_t)blockIdx.z * Bz * KACT * Dz;
#pragma unroll
    for (int mi = 0; mi < 4; ++mi) {
      int mbase = m0 + wm + mi * 16 + quad * 4;
#pragma unroll
      for (int ni = 0; ni < 4; ++ni) {
        int n = n0 + wn + ni * 16 + l16;
#pragma unroll
        for (int r = 0; r < 4; ++r)
          Pc[(size_t)(mbase + r) * Dz + n] = (bf16)acc[mi][ni][r];
      }
    }
  }
}

// ---- reduce partials + bias + gate + scatter: out[b,sel[m],:] = (P0+P1+b2)*gate ----
__global__ __launch_bounds__(256) void reduce_k(const bf16* __restrict__ P,
                                                const float* __restrict__ bias,
                                                const int* __restrict__ sel_idx,
                                                const float* __restrict__ gates,
                                                float* __restrict__ out) {
  int m = blockIdx.x;
  int b = m >> 10;
  int s = sel_idx[m];
  float gt = gates[m];
  int tid = threadIdx.x;
  const bf16x4* p0 = (const bf16x4*)(P + (size_t)m * Dz);
  const bf16x4* p1 = (const bf16x4*)(P + (size_t)Bz * KACT * Dz + (size_t)m * Dz);
  const float4* bv = (const float4*)bias;
  float4* orow = (float4*)(out + ((size_t)b * Sz + s) * Dz);
  bf16x4 a = p0[tid], c = p1[tid];
  float4 bb = bv[tid];
  float4 o;
  o.x = ((float)a[0] + (float)c[0] + bb.x) * gt;
  o.y = ((float)a[1] + (float)c[1] + bb.y) * gt;
  o.z = ((float)a[2] + (float)c[2] + bb.z) * gt;
  o.w = ((float)a[3] + (float)c[3] + bb.w) * gt;
  orow[tid] = o;
}

extern "C" void kernel_launch(void* const* d_in, const int* in_sizes, int n_in,
                              void* d_out, int out_size, void* d_ws, size_t ws_size,
                              hipStream_t stream) {
  (void)in_sizes; (void)n_in; (void)out_size; (void)ws_size;
  const float* x  = (const float*)d_in[0];
  const float* rw = (const float*)d_in[1];
  const float* rb = (const float*)d_in[2];
  const float* w1 = (const float*)d_in[3];
  const float* b1 = (const float*)d_in[4];
  const float* w2 = (const float*)d_in[5];
  const float* b2 = (const float*)d_in[6];
  float* out = (float*)d_out;

  char* ws = (char*)d_ws;
  float* scores = (float*)ws;  ws += (size_t)Bz * Sz * 4;          // 64 KB
  int*   sel_idx = (int*)ws;   ws += (size_t)Bz * KACT * 4;        // 16 KB
  float* gates = (float*)ws;   ws += (size_t)Bz * KACT * 4;        // 16 KB
  bf16*  w2T = (bf16*)ws;      ws += (size_t)Dz * DFFz * 2;        // 8 MB  [1024][4096]
  bf16*  H = (bf16*)ws;        ws += (size_t)Bz * KACT * DFFz * 2; // 32 MB [4096][4096]
  bf16*  w1T = (bf16*)ws;      ws += (size_t)DFFz * Dz * 2;        // 8 MB  [4096][1024]
  bf16*  Xsel = (bf16*)ws;     ws += (size_t)Bz * KACT * Dz * 2;   // 8 MB  [4096][1024]
  // P (2 x 8 MB bf16 partials) overlays w1T+Xsel, both dead after gemm1.
  bf16*  P = w1T;

  prep_k<<<3 * 4096, 256, 0, stream>>>(x, rw, rb, scores, (float4*)out, w1, w1T, w2, w2T);
  select_gather_k<<<Bz * (Sz / 16), 256, 0, stream>>>(x, scores, sel_idx, gates, Xsel);
  gemm1_k<<<dim3(DFFz / 128, (Bz * KACT) / 128), 512, 0, stream>>>(Xsel, w1T, b1, H);
  gemm2_k<<<dim3(Dz / 128, (Bz * KACT) / 128, 2), 512, 0, stream>>>(H, w2T, P);
  reduce_k<<<Bz * KACT, 256, 0, stream>>>(P, b2, sel_idx, gates, out);
}